// Round 7
// baseline (246.337 us; speedup 1.0000x reference)
//
#include <hip/hip_runtime.h>
#include <math.h>

// LocalityAttention, fp16 single-pass MFMA.
// Algebra: softmax(Q K^T) = softmax(q G k^T + colterm), G = Wq^T Wk;
// KG = k G^T replaces the K projection; Q projection eliminated.
// Round 7: fp32->fp16 conversion fused into GEMM staging (CVT operands are
// reg-staged: global_load fp32 -> cvt -> ds_write_b128; non-CVT operands use
// global_load_lds). Double-buffered: issue(t+1) -> compute(t) -> commit(t+1)
// -> syncthreads. Eliminates the 63 us tof16 pass entirely.

typedef _Float16 f16x8 __attribute__((ext_vector_type(8)));
typedef _Float16 f16x4 __attribute__((ext_vector_type(4)));
typedef __attribute__((ext_vector_type(4))) float f32x4;

template<typename T>
__device__ __forceinline__ void async_copy16(T* lds, const T* g) {
    __builtin_amdgcn_global_load_lds(
        (const __attribute__((address_space(1))) unsigned int*)g,
        (__attribute__((address_space(3))) unsigned int*)lds, 16, 0, 0);
}

#define BM 128
#define BN 128
#define BK 32

// C[m,n] = sum_k A[m,k]*B[n,k]  (B staged row-major [n][k])
// EPI: 0 fp32->C0; 1 fp16->C0.  BIAS: 0 none; 1 bias[col]; 2 bias[row].
// CVTA/CVTB: operand given as fp32; converted to fp16 during staging.
template<int EPI, int BIAS, int CVTA, int CVTB>
__global__ __launch_bounds__(256, 2)
void mfma_gemm(const void* __restrict__ Ap, const void* __restrict__ Bp,
               const float* __restrict__ bias, void* __restrict__ C0,
               int K, int lda, int ldb, int ldc,
               long long sA, long long sB, long long sC)
{
    __shared__ _Float16 sA2[2][BM * BK];
    __shared__ _Float16 sB2[2][BN * BK];

    const int tid = threadIdx.x;

    // XCD-chunked bijective swizzle (skip when nwg%8 != 0, e.g. G GEMM's 36).
    const int gx = gridDim.x, gy = gridDim.y;
    const int nwg = gx * gy * gridDim.z;
    const int p = blockIdx.x + gx * (blockIdx.y + gy * blockIdx.z);
    const int cpx = nwg >> 3;
    const int l = (nwg & 7) ? p : (p & 7) * cpx + (p >> 3);
    const int bx = l % gx;
    const int by = (l / gx) % gy;
    const long long bz = l / (gx * gy);

    const int m0 = by * BM;
    const int n0 = bx * BN;

    const _Float16* A0h = (const _Float16*)Ap + (CVTA ? 0 : bz * sA);
    const float*    A0f = (const float*)Ap    + (CVTA ? bz * sA : 0);
    const _Float16* B0h = (const _Float16*)Bp + (CVTB ? 0 : bz * sB);
    const float*    B0f = (const float*)Bp    + (CVTB ? bz * sB : 0);

    // loader: one 16B fp16 chunk per thread per it; global source address is
    // pre-swizzled (gsl), LDS dest linear (loff) -> read side sees XOR-swizzle.
    const int lrow  = tid >> 2;
    const int lslot = tid & 3;

    const int lane = tid & 63;
    const int wv   = tid >> 6;
    const int wm   = wv >> 1, wn = wv & 1;
    const int fr   = lane & 15;
    const int fs   = lane >> 4;
    const int sw   = fs ^ (fr & 3);
    const int abase = (wm * 64 + fr) * BK + sw * 8;
    const int bbase = (wn * 64 + fr) * BK + sw * 8;

    float4 ra[2][2];   // in-flight fp32 A chunks (CVTA)
    float4 rb[2][2];   // in-flight fp32 B chunks (CVTB)

    auto issue = [&](int nb, int t) {
        const int kt = t * BK;
        #pragma unroll
        for (int it = 0; it < 2; ++it) {
            const int row = lrow + it * 64;
            const int gsl = (lslot ^ (row & 3)) << 3;
            const size_t loff = (size_t)tid * 8 + (size_t)it * 2048;
            if (CVTA) {
                const float* src = A0f + (size_t)(m0 + row) * lda + kt + gsl;
                ra[it][0] = *(const float4*)src;
                ra[it][1] = *(const float4*)(src + 4);
            } else {
                async_copy16(&sA2[nb][loff], A0h + (size_t)(m0 + row) * lda + kt + gsl);
            }
            if (CVTB) {
                const float* src = B0f + (size_t)(n0 + row) * ldb + kt + gsl;
                rb[it][0] = *(const float4*)src;
                rb[it][1] = *(const float4*)(src + 4);
            } else {
                async_copy16(&sB2[nb][loff], B0h + (size_t)(n0 + row) * ldb + kt + gsl);
            }
        }
    };
    auto commit = [&](int nb) {
        if (!(CVTA || CVTB)) return;
        #pragma unroll
        for (int it = 0; it < 2; ++it) {
            const size_t loff = (size_t)tid * 8 + (size_t)it * 2048;
            if (CVTA) {
                f16x8 o;
                o[0] = (_Float16)ra[it][0].x; o[1] = (_Float16)ra[it][0].y;
                o[2] = (_Float16)ra[it][0].z; o[3] = (_Float16)ra[it][0].w;
                o[4] = (_Float16)ra[it][1].x; o[5] = (_Float16)ra[it][1].y;
                o[6] = (_Float16)ra[it][1].z; o[7] = (_Float16)ra[it][1].w;
                *(f16x8*)&sA2[nb][loff] = o;
            }
            if (CVTB) {
                f16x8 o;
                o[0] = (_Float16)rb[it][0].x; o[1] = (_Float16)rb[it][0].y;
                o[2] = (_Float16)rb[it][0].z; o[3] = (_Float16)rb[it][0].w;
                o[4] = (_Float16)rb[it][1].x; o[5] = (_Float16)rb[it][1].y;
                o[6] = (_Float16)rb[it][1].z; o[7] = (_Float16)rb[it][1].w;
                *(f16x8*)&sB2[nb][loff] = o;
            }
        }
    };

    f32x4 acc[4][4] = {};
    const int nt = K / BK;

    // prologue: tile 0 (full stall, once)
    issue(0, 0);
    commit(0);
    __syncthreads();    // drains vmcnt (gload_lds) + lgkm (ds_write)

    int cur = 0;
    for (int t = 0; t < nt; ++t) {
        if (t + 1 < nt) issue(cur ^ 1, t + 1);   // loads fly during compute

        const _Float16* sa = sA2[cur];
        const _Float16* sb = sB2[cur];
        f16x8 ah[4], bh[4];
        #pragma unroll
        for (int i = 0; i < 4; ++i) {
            ah[i] = *(const f16x8*)&sa[abase + i * 512];
            bh[i] = *(const f16x8*)&sb[bbase + i * 512];
        }
        #pragma unroll
        for (int mi = 0; mi < 4; ++mi)
            #pragma unroll
            for (int ni = 0; ni < 4; ++ni)
                acc[mi][ni] = __builtin_amdgcn_mfma_f32_16x16x32_f16(
                    ah[mi], bh[ni], acc[mi][ni], 0, 0, 0);

        if (t + 1 < nt) commit(cur ^ 1);  // compiler waits the reg loads here
        __syncthreads();                  // full drain: safe buffer rotation
        cur ^= 1;
    }

    // D mapping: row=(lane>>4)*4+r, col=lane&15
    const int er = fs * 4;
    #pragma unroll
    for (int mi = 0; mi < 4; ++mi) {
        #pragma unroll
        for (int ni = 0; ni < 4; ++ni) {
            const int col = n0 + wn * 64 + ni * 16 + fr;
            #pragma unroll
            for (int r = 0; r < 4; ++r) {
                const int row = m0 + wm * 64 + mi * 16 + er + r;
                float vv = acc[mi][ni][r];
                if (BIAS == 1) vv += bias[col];
                if (BIAS == 2) vv += bias[row];
                const size_t idx = (size_t)bz * sC + (size_t)row * ldc + col;
                if (EPI == 0) ((float*)C0)[idx] = vv;
                else          ((_Float16*)C0)[idx] = (_Float16)vv;
            }
        }
    }
}

// fp32 -> fp16 convert (only for Wv, tiny)
__global__ __launch_bounds__(256)
void tof16_kernel(const float* __restrict__ src, _Float16* __restrict__ dst,
                  long long n)
{
    long long i = ((long long)blockIdx.x * 256 + threadIdx.x) * 8;
    const long long stride = (long long)gridDim.x * 2048;
    for (; i < n; i += stride) {
        const float4 a = *(const float4*)&src[i];
        const float4 b = *(const float4*)&src[i + 4];
        f16x8 o;
        o[0] = (_Float16)a.x; o[1] = (_Float16)a.y;
        o[2] = (_Float16)a.z; o[3] = (_Float16)a.w;
        o[4] = (_Float16)b.x; o[5] = (_Float16)b.y;
        o[6] = (_Float16)b.z; o[7] = (_Float16)b.w;
        *(f16x8*)&dst[i] = o;
    }
}

// 64x64-tile transpose to fp16: dst[c][r] = src[r][c]; n=768
__global__ __launch_bounds__(256)
void transpose_f16(const float* __restrict__ src, _Float16* __restrict__ dst, int n)
{
    __shared__ float t[64][65];
    const int tx = threadIdx.x & 63, ty = threadIdx.x >> 6;
    const int r0 = blockIdx.y * 64, c0 = blockIdx.x * 64;
    #pragma unroll
    for (int r = 0; r < 16; ++r) {
        const int row = ty * 16 + r;
        t[row][tx] = src[(size_t)(r0 + row) * n + c0 + tx];
    }
    __syncthreads();
    #pragma unroll
    for (int r = 0; r < 16; ++r) {
        const int orow = ty * 16 + r;
        dst[(size_t)(c0 + orow) * n + r0 + tx] = (_Float16)t[tx][orow];
    }
}

// colvec[d] = sum_e WkT[d][e]*bq[e]
__global__ __launch_bounds__(256)
void colvec_kernel(const _Float16* __restrict__ WkT, const float* __restrict__ bq,
                   float* __restrict__ colvec, int n)
{
    const int wv = threadIdx.x >> 6, lane = threadIdx.x & 63;
    const int d = blockIdx.x * 4 + wv;
    float s = 0.f;
    for (int e = lane; e < n; e += 64)
        s += (float)WkT[(size_t)d * n + e] * bq[e];
    #pragma unroll
    for (int off = 32; off; off >>= 1) s += __shfl_down(s, off, 64);
    if (lane == 0) colvec[d] = s;
}

// cterm[row] = dot(k[row,:], colvec)  (fp32 inputs)
__global__ __launch_bounds__(256)
void cterm_kernel(const float* __restrict__ k, const float* __restrict__ colvec,
                  float* __restrict__ cterm)
{
    const int wv = threadIdx.x >> 6, lane = threadIdx.x & 63;
    const long long row = (long long)blockIdx.x * 4 + wv;
    const float* kp = k + row * 768;
    float s = 0.f;
    #pragma unroll
    for (int i = 0; i < 3; ++i) {
        const float4 a = *(const float4*)&kp[lane * 4 + i * 256];
        const float4 c = *(const float4*)&colvec[lane * 4 + i * 256];
        s += a.x * c.x + a.y * c.y + a.z * c.z + a.w * c.w;
    }
    #pragma unroll
    for (int off = 32; off; off >>= 1) s += __shfl_down(s, off, 64);
    if (lane == 0) cterm[row] = s;
}

// Row softmax with diag mask + per-column bias term; reads fp32 row, writes
// fp16 P in place over the first quarter of the row (reads precede writes).
__global__ __launch_bounds__(256)
void softmax_diag(float* __restrict__ P, const float* __restrict__ tptr,
                  const float* __restrict__ cterm, int S)
{
    const int row = blockIdx.x;           // b*S + i
    const int i   = row % S;
    float* rp = P + (long long)row * S;
    const int tid = threadIdx.x;
    const float invt = 1.0f / tptr[0];

    const float4 v  = *(const float4*)&rp[tid * 4];
    const float4 ct = *(const float4*)&cterm[(long long)(row / S) * S + tid * 4];
    float vals[4] = {v.x + ct.x, v.y + ct.y, v.z + ct.z, v.w + ct.w};
    #pragma unroll
    for (int j = 0; j < 4; ++j) {
        vals[j] *= invt;
        if (tid * 4 + j == i) vals[j] = -INFINITY;
    }

    float mx = fmaxf(fmaxf(vals[0], vals[1]), fmaxf(vals[2], vals[3]));
    #pragma unroll
    for (int off = 32; off > 0; off >>= 1)
        mx = fmaxf(mx, __shfl_down(mx, off, 64));

    __shared__ float smax[4], ssum[4];
    const int wv = tid >> 6, ln = tid & 63;
    if (ln == 0) smax[wv] = mx;
    __syncthreads();
    mx = fmaxf(fmaxf(smax[0], smax[1]), fmaxf(smax[2], smax[3]));

    float e[4];
    float s = 0.f;
    #pragma unroll
    for (int j = 0; j < 4; ++j) { e[j] = expf(vals[j] - mx); s += e[j]; }
    #pragma unroll
    for (int off = 32; off > 0; off >>= 1)
        s += __shfl_down(s, off, 64);
    if (ln == 0) ssum[wv] = s;
    __syncthreads();
    s = ssum[0] + ssum[1] + ssum[2] + ssum[3];

    const float inv = 1.0f / s;
    f16x4 o;
    o[0] = (_Float16)(e[0] * inv);
    o[1] = (_Float16)(e[1] * inv);
    o[2] = (_Float16)(e[2] * inv);
    o[3] = (_Float16)(e[3] * inv);
    *(f16x4*)&((_Float16*)rp)[tid * 4] = o;
}

extern "C" void kernel_launch(void* const* d_in, const int* in_sizes, int n_in,
                              void* d_out, int out_size, void* d_ws, size_t ws_size,
                              hipStream_t stream)
{
    const float* q    = (const float*)d_in[0];
    const float* k    = (const float*)d_in[1];
    const float* v    = (const float*)d_in[2];
    const float* Wq   = (const float*)d_in[3];
    const float* bq   = (const float*)d_in[4];
    const float* Wk   = (const float*)d_in[5];
    const float* bk   = (const float*)d_in[6];   // row-constant -> cancels in softmax
    const float* Wv   = (const float*)d_in[7];
    const float* bv   = (const float*)d_in[8];
    const float* temp = (const float*)d_in[9];
    (void)bk;

    const int S = 1024, D = 768;
    const long long nW = (long long)D * D;       // 589,824

    // ws layout (bytes), end ~122.5 MB (< proven 202 MB). No aliasing.
    char* ws = (char*)d_ws;
    _Float16* VT  = (_Float16*)(ws + 0);          // 24 MB
    _Float16* KG  = (_Float16*)(ws + 25165824);   // 24 MB
    float*  scores = (float*)(ws + 50331648);     // 64 MiB
    _Float16* wvh = (_Float16*)(ws + 117440512);  // 1.125 MB
    _Float16* WqT = (_Float16*)(ws + 118620160);
    _Float16* WkT = (_Float16*)(ws + 119799808);
    _Float16* G   = (_Float16*)(ws + 120979456);
    float* colvec = (float*)(ws + 122159104);
    float* cterm  = (float*)(ws + 122162176);

    dim3 blk(256);

    // small weight prep
    tof16_kernel<<<288, blk, 0, stream>>>(Wv, wvh, nW);
    transpose_f16<<<dim3(12, 12), blk, 0, stream>>>(Wq, WqT, D);
    transpose_f16<<<dim3(12, 12), blk, 0, stream>>>(Wk, WkT, D);

    // bias column-term: colvec = WkT*bq ; cterm[b,j] = k[b,j]·colvec
    colvec_kernel<<<192,  blk, 0, stream>>>(WkT, bq, colvec, D);
    cterm_kernel <<<4096, blk, 0, stream>>>(k, colvec, cterm);

    // VT[b][e][s] = sum_d Wv[e,d] v[b,s,d] + bv[e]   (B = v fp32, CVTB)
    mfma_gemm<1, 2, 0, 1><<<dim3(8, 6, 16), blk, 0, stream>>>(
        wvh, v, bv, VT,
        768, 768, 768, 1024, 0, (long long)S * D, (long long)D * S);

    // G[d,d'] = sum_e Wq[e,d] Wk[e,d']
    mfma_gemm<1, 0, 0, 0><<<dim3(6, 6, 1), blk, 0, stream>>>(
        WqT, WkT, nullptr, G,
        768, 768, 768, 768, 0, 0, 0);

    // KG[j,d] = sum_d' k[j,d'] G[d,d']   (A = k fp32, CVTA; M = 16384 flat)
    mfma_gemm<1, 0, 1, 0><<<dim3(6, 128, 1), blk, 0, stream>>>(
        k, G, nullptr, KG,
        768, 768, 768, 768, 0, 0, 0);

    // scores[b] = q[b] (KG[b])^T   (A = q fp32, CVTA)
    mfma_gemm<0, 0, 1, 0><<<dim3(8, 8, 16), blk, 0, stream>>>(
        q, KG, nullptr, scores,
        768, 768, 768, 1024,
        (long long)S * D, (long long)S * D, (long long)S * S);

    // masked softmax (+ column bias term), fp16 P written in place
    softmax_diag<<<16 * S, blk, 0, stream>>>(scores, temp, cterm, S);

    // out[b] = P[b] VT[b]^T   (P rows: 1024 fp16 in a 4096B-stride row)
    mfma_gemm<0, 0, 0, 0><<<dim3(6, 8, 16), blk, 0, stream>>>(
        scores, VT, nullptr, d_out,
        1024, 2048, 1024, 768,
        2LL * S * S, (long long)D * S, (long long)S * D);
}

// Round 8
// 239.720 us; speedup vs baseline: 1.0276x; 1.0276x over previous
//
#include <hip/hip_runtime.h>
#include <math.h>

// LocalityAttention, fp16 single-pass MFMA.
// Algebra: softmax(Q K^T) = softmax(q G k^T + colterm), G = Wq^T Wk;
// KG = k G^T replaces the K projection; Q projection eliminated.
// Round 8: CVT-fusion reverted (regressed scores 47->80: per-tile fp32
// reload+cvt doesn't amortize over panel reuse). Fixes: exact-cover convert
// grid (no grid-stride iterations) and XCD-matched swizzle on softmax so it
// reads scores from the same XCD's L2 that the scores GEMM wrote.

typedef _Float16 f16x8 __attribute__((ext_vector_type(8)));
typedef _Float16 f16x4 __attribute__((ext_vector_type(4)));
typedef __attribute__((ext_vector_type(4))) float f32x4;

template<typename T>
__device__ __forceinline__ void async_copy16(T* lds, const T* g) {
    __builtin_amdgcn_global_load_lds(
        (const __attribute__((address_space(1))) unsigned int*)g,
        (__attribute__((address_space(3))) unsigned int*)lds, 16, 0, 0);
}

#define BM 128
#define BN 128
#define BK 32

// C[m,n] = sum_k A[m,k]*B[n,k]  (B staged row-major [n][k])
// EPI: 0 fp32->C0; 1 fp16->C0.  BIAS: 0 none; 1 bias[col]; 2 bias[row].
template<int EPI, int BIAS>
__global__ __launch_bounds__(256, 2)
void mfma_gemm(const _Float16* __restrict__ A, const _Float16* __restrict__ B,
               const float* __restrict__ bias,
               void* __restrict__ C0,
               int K, int lda, int ldb, int ldc,
               long long sA, long long sB, long long sC)
{
    __shared__ _Float16 sAh[BM * BK];
    __shared__ _Float16 sBh[BN * BK];

    const int tid = threadIdx.x;

    // XCD-chunked bijective swizzle (skip when nwg%8 != 0, e.g. G GEMM's 36).
    const int gx = gridDim.x, gy = gridDim.y;
    const int nwg = gx * gy * gridDim.z;
    const int p = blockIdx.x + gx * (blockIdx.y + gy * blockIdx.z);
    const int cpx = nwg >> 3;
    const int l = (nwg & 7) ? p : (p & 7) * cpx + (p >> 3);
    const int bx = l % gx;
    const int by = (l / gx) % gy;
    const long long bz = l / (gx * gy);

    const int m0 = by * BM;
    const int n0 = bx * BN;

    const _Float16* A0 = A + bz * sA;
    const _Float16* B0 = B + bz * sB;

    // loader: one 16B chunk per thread per it; global source pre-swizzled,
    // LDS dest linear -> read side sees XOR-swizzle.
    const int lrow  = tid >> 2;
    const int lslot = tid & 3;

    const int lane = tid & 63;
    const int wv   = tid >> 6;
    const int wm   = wv >> 1, wn = wv & 1;
    const int fr   = lane & 15;
    const int fs   = lane >> 4;
    const int sw   = fs ^ (fr & 3);
    const int abase = (wm * 64 + fr) * BK + sw * 8;
    const int bbase = (wn * 64 + fr) * BK + sw * 8;

    f32x4 acc[4][4] = {};

    for (int kt = 0; kt < K; kt += BK) {
        #pragma unroll
        for (int it = 0; it < 2; ++it) {
            const int row = lrow + it * 64;
            const int gsl = (lslot ^ (row & 3)) << 3;
            const size_t loff = (size_t)tid * 8 + (size_t)it * 2048;
            async_copy16(&sAh[loff], A0 + (size_t)(m0 + row) * lda + kt + gsl);
            async_copy16(&sBh[loff], B0 + (size_t)(n0 + row) * ldb + kt + gsl);
        }
        __syncthreads();

        f16x8 ah[4], bh[4];
        #pragma unroll
        for (int i = 0; i < 4; ++i) {
            ah[i] = *(const f16x8*)&sAh[abase + i * 512];
            bh[i] = *(const f16x8*)&sBh[bbase + i * 512];
        }
        #pragma unroll
        for (int mi = 0; mi < 4; ++mi)
            #pragma unroll
            for (int ni = 0; ni < 4; ++ni)
                acc[mi][ni] = __builtin_amdgcn_mfma_f32_16x16x32_f16(
                    ah[mi], bh[ni], acc[mi][ni], 0, 0, 0);
        __syncthreads();
    }

    // D mapping: row=(lane>>4)*4+r, col=lane&15
    const int er = fs * 4;
    #pragma unroll
    for (int mi = 0; mi < 4; ++mi) {
        #pragma unroll
        for (int ni = 0; ni < 4; ++ni) {
            const int col = n0 + wn * 64 + ni * 16 + fr;
            #pragma unroll
            for (int r = 0; r < 4; ++r) {
                const int row = m0 + wm * 64 + mi * 16 + er + r;
                float vv = acc[mi][ni][r];
                if (BIAS == 1) vv += bias[col];
                if (BIAS == 2) vv += bias[row];
                const size_t idx = (size_t)bz * sC + (size_t)row * ldc + col;
                if (EPI == 0) ((float*)C0)[idx] = vv;
                else          ((_Float16*)C0)[idx] = (_Float16)vv;
            }
        }
    }
}

// fused fp32 -> fp16 convert for q,k,v; exact-cover grid, no loop.
__global__ __launch_bounds__(256)
void tof16_3(const float* __restrict__ q, const float* __restrict__ k,
             const float* __restrict__ v,
             _Float16* __restrict__ qh, _Float16* __restrict__ kh,
             _Float16* __restrict__ vh)
{
    const float* src = blockIdx.z == 0 ? q : blockIdx.z == 1 ? k : v;
    _Float16* dst    = blockIdx.z == 0 ? qh : blockIdx.z == 1 ? kh : vh;
    const long long i = ((long long)blockIdx.x * 256 + threadIdx.x) * 8;
    const float4 a = *(const float4*)&src[i];
    const float4 b = *(const float4*)&src[i + 4];
    f16x8 o;
    o[0] = (_Float16)a.x; o[1] = (_Float16)a.y;
    o[2] = (_Float16)a.z; o[3] = (_Float16)a.w;
    o[4] = (_Float16)b.x; o[5] = (_Float16)b.y;
    o[6] = (_Float16)b.z; o[7] = (_Float16)b.w;
    *(f16x8*)&dst[i] = o;
}

// fp32 -> fp16 convert (only for Wv, tiny)
__global__ __launch_bounds__(256)
void tof16_kernel(const float* __restrict__ src, _Float16* __restrict__ dst,
                  long long n)
{
    long long i = ((long long)blockIdx.x * 256 + threadIdx.x) * 8;
    const long long stride = (long long)gridDim.x * 2048;
    for (; i < n; i += stride) {
        const float4 a = *(const float4*)&src[i];
        const float4 b = *(const float4*)&src[i + 4];
        f16x8 o;
        o[0] = (_Float16)a.x; o[1] = (_Float16)a.y;
        o[2] = (_Float16)a.z; o[3] = (_Float16)a.w;
        o[4] = (_Float16)b.x; o[5] = (_Float16)b.y;
        o[6] = (_Float16)b.z; o[7] = (_Float16)b.w;
        *(f16x8*)&dst[i] = o;
    }
}

// 64x64-tile transpose to fp16: dst[c][r] = src[r][c]; n=768
__global__ __launch_bounds__(256)
void transpose_f16(const float* __restrict__ src, _Float16* __restrict__ dst, int n)
{
    __shared__ float t[64][65];
    const int tx = threadIdx.x & 63, ty = threadIdx.x >> 6;
    const int r0 = blockIdx.y * 64, c0 = blockIdx.x * 64;
    #pragma unroll
    for (int r = 0; r < 16; ++r) {
        const int row = ty * 16 + r;
        t[row][tx] = src[(size_t)(r0 + row) * n + c0 + tx];
    }
    __syncthreads();
    #pragma unroll
    for (int r = 0; r < 16; ++r) {
        const int orow = ty * 16 + r;
        dst[(size_t)(c0 + orow) * n + r0 + tx] = (_Float16)t[tx][orow];
    }
}

// colvec[d] = sum_e WkT[d][e]*bq[e]
__global__ __launch_bounds__(256)
void colvec_kernel(const _Float16* __restrict__ WkT, const float* __restrict__ bq,
                   float* __restrict__ colvec, int n)
{
    const int wv = threadIdx.x >> 6, lane = threadIdx.x & 63;
    const int d = blockIdx.x * 4 + wv;
    float s = 0.f;
    for (int e = lane; e < n; e += 64)
        s += (float)WkT[(size_t)d * n + e] * bq[e];
    #pragma unroll
    for (int off = 32; off; off >>= 1) s += __shfl_down(s, off, 64);
    if (lane == 0) colvec[d] = s;
}

// cterm[row] = dot(k[row,:], colvec)  (fp32 inputs)
__global__ __launch_bounds__(256)
void cterm_kernel(const float* __restrict__ k, const float* __restrict__ colvec,
                  float* __restrict__ cterm)
{
    const int wv = threadIdx.x >> 6, lane = threadIdx.x & 63;
    const long long row = (long long)blockIdx.x * 4 + wv;
    const float* kp = k + row * 768;
    float s = 0.f;
    #pragma unroll
    for (int i = 0; i < 3; ++i) {
        const float4 a = *(const float4*)&kp[lane * 4 + i * 256];
        const float4 c = *(const float4*)&colvec[lane * 4 + i * 256];
        s += a.x * c.x + a.y * c.y + a.z * c.z + a.w * c.w;
    }
    #pragma unroll
    for (int off = 32; off; off >>= 1) s += __shfl_down(s, off, 64);
    if (lane == 0) cterm[row] = s;
}

// Row softmax with diag mask + per-column bias term; reads fp32 row, writes
// fp16 P in place over the first quarter of the row. Block id is XCD-swizzled
// with the same chunk map as the scores GEMM (batches 2x,2x+1 -> XCD x) so
// the row is read from the local XCD's L2.
__global__ __launch_bounds__(256)
void softmax_diag(float* __restrict__ P, const float* __restrict__ tptr,
                  const float* __restrict__ cterm, int S)
{
    const int p = blockIdx.x;                       // 16384 = 8 * 2048
    const int row = (p & 7) * (16 * 1024 / 8) + (p >> 3);
    const int i   = row % S;
    float* rp = P + (long long)row * S;
    const int tid = threadIdx.x;
    const float invt = 1.0f / tptr[0];

    const float4 v  = *(const float4*)&rp[tid * 4];
    const float4 ct = *(const float4*)&cterm[(long long)(row / S) * S + tid * 4];
    float vals[4] = {v.x + ct.x, v.y + ct.y, v.z + ct.z, v.w + ct.w};
    #pragma unroll
    for (int j = 0; j < 4; ++j) {
        vals[j] *= invt;
        if (tid * 4 + j == i) vals[j] = -INFINITY;
    }

    float mx = fmaxf(fmaxf(vals[0], vals[1]), fmaxf(vals[2], vals[3]));
    #pragma unroll
    for (int off = 32; off > 0; off >>= 1)
        mx = fmaxf(mx, __shfl_down(mx, off, 64));

    __shared__ float smax[4], ssum[4];
    const int wv = tid >> 6, ln = tid & 63;
    if (ln == 0) smax[wv] = mx;
    __syncthreads();
    mx = fmaxf(fmaxf(smax[0], smax[1]), fmaxf(smax[2], smax[3]));

    float e[4];
    float s = 0.f;
    #pragma unroll
    for (int j = 0; j < 4; ++j) { e[j] = expf(vals[j] - mx); s += e[j]; }
    #pragma unroll
    for (int off = 32; off > 0; off >>= 1)
        s += __shfl_down(s, off, 64);
    if (ln == 0) ssum[wv] = s;
    __syncthreads();
    s = ssum[0] + ssum[1] + ssum[2] + ssum[3];

    const float inv = 1.0f / s;
    f16x4 o;
    o[0] = (_Float16)(e[0] * inv);
    o[1] = (_Float16)(e[1] * inv);
    o[2] = (_Float16)(e[2] * inv);
    o[3] = (_Float16)(e[3] * inv);
    *(f16x4*)&((_Float16*)rp)[tid * 4] = o;
}

extern "C" void kernel_launch(void* const* d_in, const int* in_sizes, int n_in,
                              void* d_out, int out_size, void* d_ws, size_t ws_size,
                              hipStream_t stream)
{
    const float* q    = (const float*)d_in[0];
    const float* k    = (const float*)d_in[1];
    const float* v    = (const float*)d_in[2];
    const float* Wq   = (const float*)d_in[3];
    const float* bq   = (const float*)d_in[4];
    const float* Wk   = (const float*)d_in[5];
    const float* bk   = (const float*)d_in[6];   // row-constant -> cancels in softmax
    const float* Wv   = (const float*)d_in[7];
    const float* bv   = (const float*)d_in[8];
    const float* temp = (const float*)d_in[9];
    (void)bk;

    const int S = 1024, D = 768;
    const long long nW = (long long)D * D;       // 589,824

    // ws layout (bytes), end 197,725,184 (< proven 202,574,848). No aliasing.
    char* ws = (char*)d_ws;
    _Float16* qh  = (_Float16*)(ws + 0);          // 24 MB
    _Float16* kh  = (_Float16*)(ws + 25165824);   // 24 MB
    _Float16* vh  = (_Float16*)(ws + 50331648);   // 24 MB
    _Float16* VT  = (_Float16*)(ws + 75497472);   // 24 MB
    _Float16* KG  = (_Float16*)(ws + 100663296);  // 24 MB
    float*  scores = (float*)(ws + 125829120);    // 64 MiB
    _Float16* wvh = (_Float16*)(ws + 192937984);  // 1.125 MB
    _Float16* WqT = (_Float16*)(ws + 194117632);
    _Float16* WkT = (_Float16*)(ws + 195297280);
    _Float16* G   = (_Float16*)(ws + 196476928);
    float* colvec = (float*)(ws + 197656576);
    float* cterm  = (float*)(ws + 197659648);

    dim3 blk(256);

    // input conversions / transposes (6144 blocks x 2048 elems = exactly nE)
    tof16_3<<<dim3(6144, 1, 3), blk, 0, stream>>>(q, k, v, qh, kh, vh);
    tof16_kernel<<<288, blk, 0, stream>>>(Wv, wvh, nW);
    transpose_f16<<<dim3(12, 12), blk, 0, stream>>>(Wq, WqT, D);
    transpose_f16<<<dim3(12, 12), blk, 0, stream>>>(Wk, WkT, D);

    // bias column-term: colvec = WkT*bq ; cterm[b,j] = k[b,j]·colvec
    colvec_kernel<<<192,  blk, 0, stream>>>(WkT, bq, colvec, D);
    cterm_kernel <<<4096, blk, 0, stream>>>(k, colvec, cterm);

    // VT[b][e][s] = sum_d Wv[e,d] v[b,s,d] + bv[e]
    mfma_gemm<1, 2><<<dim3(8, 6, 16), blk, 0, stream>>>(
        wvh, vh, bv, VT,
        768, 768, 768, 1024, 0, (long long)S * D, (long long)D * S);

    // G[d,d'] = sum_e Wq[e,d] Wk[e,d']
    mfma_gemm<1, 0><<<dim3(6, 6, 1), blk, 0, stream>>>(
        WqT, WkT, nullptr, G,
        768, 768, 768, 768, 0, 0, 0);

    // KG[j,d] = sum_d' k[j,d'] G[d,d']  (M = 16384 flat)
    mfma_gemm<1, 0><<<dim3(6, 128, 1), blk, 0, stream>>>(
        kh, G, nullptr, KG,
        768, 768, 768, 768, 0, 0, 0);

    // scores[b] = q[b] (KG[b])^T
    mfma_gemm<0, 0><<<dim3(8, 8, 16), blk, 0, stream>>>(
        qh, KG, nullptr, scores,
        768, 768, 768, 1024,
        (long long)S * D, (long long)S * D, (long long)S * S);

    // masked softmax (+ column bias term), fp16 P written in place
    softmax_diag<<<16 * S, blk, 0, stream>>>(scores, temp, cterm, S);

    // out[b] = P[b] VT[b]^T   (P rows: 1024 fp16 in a 4096B-stride row)
    mfma_gemm<0, 0><<<dim3(6, 8, 16), blk, 0, stream>>>(
        (const _Float16*)scores, VT, nullptr, d_out,
        1024, 2048, 1024, 768,
        2LL * S * S, (long long)D * S, (long long)S * D);
}

// Round 9
// 226.261 us; speedup vs baseline: 1.0887x; 1.0595x over previous
//
#include <hip/hip_runtime.h>
#include <math.h>

// LocalityAttention, fp16 single-pass MFMA.
// Algebra: softmax(Q K^T) = softmax(q G k^T + colterm), G = Wq^T Wk;
// KG = k G^T replaces the K projection; Q projection eliminated.
// Round 9: the four big GEMMs (VT, KG, scores, PV) ported to a 256x256-tile
// 8-phase counted-vmcnt schedule (BK=64, 8 waves, 128 KiB LDS dbuf, T2 XOR
// swizzle, T5 setprio, vmcnt(6) only at phases 4/8). G stays on the 128² path.

typedef _Float16 f16x8 __attribute__((ext_vector_type(8)));
typedef _Float16 f16x4 __attribute__((ext_vector_type(4)));
typedef __attribute__((ext_vector_type(4))) float f32x4;

template<typename T>
__device__ __forceinline__ void async_copy16(T* lds, const T* g) {
    __builtin_amdgcn_global_load_lds(
        (const __attribute__((address_space(1))) unsigned int*)g,
        (__attribute__((address_space(3))) unsigned int*)lds, 16, 0, 0);
}

__device__ __forceinline__ void barrier_mem() {
    asm volatile("s_barrier" ::: "memory");
}

// ---------------- 256x256 8-phase GEMM: C[m,n] = sum_k A[m,k]*B[n,k] -----
// LDS per buffer: A tile 256x64 fp16 (32KB) + B tile 256x64 (32KB); 2 buffers.
// Row r slot s (16B units): physical slot = s ^ (r&7) (both sides swizzled).
// Stage unit = 8KB = 1 gload_lds/thread: B unit b = rows [64b,64b+64);
// A unit q = rows [32q,32q+32) u [128+32q,128+32q+32) (the phase-q quadrant
// strips of both wm halves -> dead exactly after phase q+1 of its tile).
// EPI: 0 fp32->C0; 1 fp16->C0.  BIAS: 0 none; 1 bias[col]; 2 bias[row].
template<int EPI, int BIAS>
__global__ __launch_bounds__(512, 2)
void mfma_gemm256(const _Float16* __restrict__ A, const _Float16* __restrict__ B,
                  const float* __restrict__ bias, void* __restrict__ C0,
                  int K, int lda, int ldb, int ldc,
                  long long sA, long long sB, long long sC)
{
    __shared__ _Float16 smem[65536];   // 128 KiB: [buf][op][256*64]

    const int tid = threadIdx.x;

    // XCD-chunked bijective swizzle (all launches have nwg % 8 == 0)
    const int gx = gridDim.x, gy = gridDim.y;
    const int nwg = gx * gy * gridDim.z;
    const int p = blockIdx.x + gx * (blockIdx.y + gy * blockIdx.z);
    const int cpx = nwg >> 3;
    const int l = (nwg & 7) ? p : (p & 7) * cpx + (p >> 3);
    const int bx = l % gx;
    const int by = (l / gx) % gy;
    const long long bz = l / (gx * gy);
    const int m0 = by * 256, n0 = bx * 256;

    const _Float16* A0 = A + bz * sA;
    const _Float16* B0 = B + bz * sB;

    const int lane = tid & 63;
    const int wid  = tid >> 6;
    const int wm   = wid >> 2;        // 0..1: A half (128 rows)
    const int wn   = wid & 3;         // 0..3: B quarter (64 rows)
    const int fr   = lane & 15;
    const int fs   = lane >> 4;

    const int nt = K / 64;            // K-tiles (12 or 16)
    const int iters = nt / 2;

    // stage one 8KB unit of tile `tile` into buffer dbuf (1 gload_lds/thread)
    auto stage_unit = [&](int dbuf, int isB, int unit, int tile) {
        if (tile >= nt) return;
        const int kt = tile * 64;
        const int lr = tid >> 3, s = tid & 7;
        const int grow = isB ? (unit * 64 + lr)
                             : (((lr >> 5) << 7) + unit * 32 + (lr & 31));
        const int gslot = s ^ (grow & 7);
        _Float16* dst = smem + dbuf * 32768 + isB * 16384 + grow * 64 + s * 8;
        const _Float16* src = (isB ? B0 : A0)
            + (size_t)((isB ? n0 : m0) + grow) * (size_t)(isB ? ldb : lda)
            + kt + gslot * 8;
        async_copy16(dst, src);
    };

    f32x4 acc[8][4] = {};
    f16x8 bf[4][2];

#define PHASE(BUF, Q, READB, STAGES, VMW) do {                                 \
    const _Float16* Ab = smem + (BUF) * 32768;                                 \
    const _Float16* Bb = Ab + 16384;                                           \
    f16x8 a0k0, a0k1, a1k0, a1k1;                                              \
    { const int r = wm * 128 + ((Q) * 2 + 0) * 16 + fr;                        \
      a0k0 = *(const f16x8*)&Ab[r * 64 + ((fs       ^ (r & 7)) * 8)];          \
      a0k1 = *(const f16x8*)&Ab[r * 64 + (((4 + fs) ^ (r & 7)) * 8)]; }        \
    { const int r = wm * 128 + ((Q) * 2 + 1) * 16 + fr;                        \
      a1k0 = *(const f16x8*)&Ab[r * 64 + ((fs       ^ (r & 7)) * 8)];          \
      a1k1 = *(const f16x8*)&Ab[r * 64 + (((4 + fs) ^ (r & 7)) * 8)]; }        \
    if (READB) {                                                               \
      _Pragma("unroll") for (int ni = 0; ni < 4; ++ni) {                       \
        const int r = wn * 64 + ni * 16 + fr;                                  \
        bf[ni][0] = *(const f16x8*)&Bb[r * 64 + ((fs       ^ (r & 7)) * 8)];   \
        bf[ni][1] = *(const f16x8*)&Bb[r * 64 + (((4 + fs) ^ (r & 7)) * 8)]; } \
    }                                                                          \
    STAGES;                                                                    \
    barrier_mem();                                                             \
    __builtin_amdgcn_s_setprio(1);                                             \
    _Pragma("unroll") for (int ni = 0; ni < 4; ++ni) {                         \
      acc[(Q)*2+0][ni] = __builtin_amdgcn_mfma_f32_16x16x32_f16(a0k0, bf[ni][0], acc[(Q)*2+0][ni], 0, 0, 0); \
      acc[(Q)*2+0][ni] = __builtin_amdgcn_mfma_f32_16x16x32_f16(a0k1, bf[ni][1], acc[(Q)*2+0][ni], 0, 0, 0); \
      acc[(Q)*2+1][ni] = __builtin_amdgcn_mfma_f32_16x16x32_f16(a1k0, bf[ni][0], acc[(Q)*2+1][ni], 0, 0, 0); \
      acc[(Q)*2+1][ni] = __builtin_amdgcn_mfma_f32_16x16x32_f16(a1k1, bf[ni][1], acc[(Q)*2+1][ni], 0, 0, 0); \
    }                                                                          \
    __builtin_amdgcn_s_setprio(0);                                             \
    VMW;                                                                       \
    barrier_mem();                                                             \
} while (0)

    // Prologue: tile0 fully into buf0 (8 units); tile1's B + A-u0,u1 into buf1.
    stage_unit(0, 0, 0, 0); stage_unit(0, 0, 1, 0);
    stage_unit(0, 0, 2, 0); stage_unit(0, 0, 3, 0);
    stage_unit(0, 1, 0, 0); stage_unit(0, 1, 1, 0);
    stage_unit(0, 1, 2, 0); stage_unit(0, 1, 3, 0);
    stage_unit(1, 1, 0, 1); stage_unit(1, 1, 1, 1);
    stage_unit(1, 1, 2, 1); stage_unit(1, 1, 3, 1);
    stage_unit(1, 0, 0, 1); stage_unit(1, 0, 1, 1);
    asm volatile("s_waitcnt vmcnt(6)" ::: "memory");  // tile0 landed
    barrier_mem();

    for (int i = 0; i < iters; ++i) {
        const int T1 = 2 * i + 1, T2 = 2 * i + 2, T3 = 2 * i + 3;
        const bool last = (i + 1 == iters);
        // tile 2i from buf0 (phases 1-4)
        PHASE(0, 0, 1, stage_unit(1, 0, 2, T1); stage_unit(1, 0, 3, T1), );
        PHASE(0, 1, 0, stage_unit(0, 1, 0, T2); stage_unit(0, 1, 1, T2), );
        PHASE(0, 2, 0, stage_unit(0, 1, 2, T2); stage_unit(0, 1, 3, T2), );
        PHASE(0, 3, 0, stage_unit(0, 0, 0, T2); stage_unit(0, 0, 1, T2),
              if (last) { asm volatile("s_waitcnt vmcnt(0)" ::: "memory"); }
              else      { asm volatile("s_waitcnt vmcnt(6)" ::: "memory"); });
        // tile 2i+1 from buf1 (phases 5-8)
        PHASE(1, 0, 1, stage_unit(0, 0, 2, T2); stage_unit(0, 0, 3, T2), );
        PHASE(1, 1, 0, stage_unit(1, 1, 0, T3); stage_unit(1, 1, 1, T3), );
        PHASE(1, 2, 0, stage_unit(1, 1, 2, T3); stage_unit(1, 1, 3, T3), );
        PHASE(1, 3, 0, stage_unit(1, 0, 0, T3); stage_unit(1, 0, 1, T3),
              asm volatile("s_waitcnt vmcnt(6)" ::: "memory"));
    }
#undef PHASE

    // Epilogue: D row = m0 + wm*128 + mi*16 + fs*4 + r, col = n0 + wn*64 + ni*16 + fr
    #pragma unroll
    for (int mi = 0; mi < 8; ++mi) {
        #pragma unroll
        for (int ni = 0; ni < 4; ++ni) {
            const int col = n0 + wn * 64 + ni * 16 + fr;
            #pragma unroll
            for (int r = 0; r < 4; ++r) {
                const int row = m0 + wm * 128 + mi * 16 + fs * 4 + r;
                float vv = acc[mi][ni][r];
                if (BIAS == 1) vv += bias[col];
                if (BIAS == 2) vv += bias[row];
                const size_t idx = (size_t)bz * sC + (size_t)row * ldc + col;
                if (EPI == 0) ((float*)C0)[idx] = vv;
                else          ((_Float16*)C0)[idx] = (_Float16)vv;
            }
        }
    }
}

// ---------------- 128x128 2-phase GEMM (kept for the tiny G matmul) ------
template<int EPI, int BIAS>
__global__ __launch_bounds__(256, 2)
void mfma_gemm(const _Float16* __restrict__ A, const _Float16* __restrict__ B,
               const float* __restrict__ bias,
               void* __restrict__ C0,
               int K, int lda, int ldb, int ldc,
               long long sA, long long sB, long long sC)
{
    __shared__ _Float16 sAh[128 * 32];
    __shared__ _Float16 sBh[128 * 32];

    const int tid = threadIdx.x;
    const int gx = gridDim.x, gy = gridDim.y;
    const int nwg = gx * gy * gridDim.z;
    const int p = blockIdx.x + gx * (blockIdx.y + gy * blockIdx.z);
    const int cpx = nwg >> 3;
    const int l = (nwg & 7) ? p : (p & 7) * cpx + (p >> 3);
    const int bx = l % gx;
    const int by = (l / gx) % gy;
    const long long bz = l / (gx * gy);

    const int m0 = by * 128;
    const int n0 = bx * 128;

    const _Float16* A0 = A + bz * sA;
    const _Float16* B0 = B + bz * sB;

    const int lrow  = tid >> 2;
    const int lslot = tid & 3;

    const int lane = tid & 63;
    const int wv   = tid >> 6;
    const int wm   = wv >> 1, wn = wv & 1;
    const int fr   = lane & 15;
    const int fs   = lane >> 4;
    const int sw   = fs ^ (fr & 3);
    const int abase = (wm * 64 + fr) * 32 + sw * 8;
    const int bbase = (wn * 64 + fr) * 32 + sw * 8;

    f32x4 acc[4][4] = {};

    for (int kt = 0; kt < K; kt += 32) {
        #pragma unroll
        for (int it = 0; it < 2; ++it) {
            const int row = lrow + it * 64;
            const int gsl = (lslot ^ (row & 3)) << 3;
            const size_t loff = (size_t)tid * 8 + (size_t)it * 2048;
            async_copy16(&sAh[loff], A0 + (size_t)(m0 + row) * lda + kt + gsl);
            async_copy16(&sBh[loff], B0 + (size_t)(n0 + row) * ldb + kt + gsl);
        }
        __syncthreads();

        f16x8 ah[4], bh[4];
        #pragma unroll
        for (int i = 0; i < 4; ++i) {
            ah[i] = *(const f16x8*)&sAh[abase + i * 512];
            bh[i] = *(const f16x8*)&sBh[bbase + i * 512];
        }
        #pragma unroll
        for (int mi = 0; mi < 4; ++mi)
            #pragma unroll
            for (int ni = 0; ni < 4; ++ni)
                acc[mi][ni] = __builtin_amdgcn_mfma_f32_16x16x32_f16(
                    ah[mi], bh[ni], acc[mi][ni], 0, 0, 0);
        __syncthreads();
    }

    const int er = fs * 4;
    #pragma unroll
    for (int mi = 0; mi < 4; ++mi) {
        #pragma unroll
        for (int ni = 0; ni < 4; ++ni) {
            const int col = n0 + wn * 64 + ni * 16 + fr;
            #pragma unroll
            for (int r = 0; r < 4; ++r) {
                const int row = m0 + wm * 64 + mi * 16 + er + r;
                float vv = acc[mi][ni][r];
                if (BIAS == 1) vv += bias[col];
                if (BIAS == 2) vv += bias[row];
                const size_t idx = (size_t)bz * sC + (size_t)row * ldc + col;
                if (EPI == 0) ((float*)C0)[idx] = vv;
                else          ((_Float16*)C0)[idx] = (_Float16)vv;
            }
        }
    }
}

// fused fp32 -> fp16 convert for q,k,v; exact-cover grid.
__global__ __launch_bounds__(256)
void tof16_3(const float* __restrict__ q, const float* __restrict__ k,
             const float* __restrict__ v,
             _Float16* __restrict__ qh, _Float16* __restrict__ kh,
             _Float16* __restrict__ vh)
{
    const float* src = blockIdx.z == 0 ? q : blockIdx.z == 1 ? k : v;
    _Float16* dst    = blockIdx.z == 0 ? qh : blockIdx.z == 1 ? kh : vh;
    const long long i = ((long long)blockIdx.x * 256 + threadIdx.x) * 8;
    const float4 a = *(const float4*)&src[i];
    const float4 b = *(const float4*)&src[i + 4];
    f16x8 o;
    o[0] = (_Float16)a.x; o[1] = (_Float16)a.y;
    o[2] = (_Float16)a.z; o[3] = (_Float16)a.w;
    o[4] = (_Float16)b.x; o[5] = (_Float16)b.y;
    o[6] = (_Float16)b.z; o[7] = (_Float16)b.w;
    *(f16x8*)&dst[i] = o;
}

// fp32 -> fp16 convert (only for Wv, tiny)
__global__ __launch_bounds__(256)
void tof16_kernel(const float* __restrict__ src, _Float16* __restrict__ dst,
                  long long n)
{
    long long i = ((long long)blockIdx.x * 256 + threadIdx.x) * 8;
    const long long stride = (long long)gridDim.x * 2048;
    for (; i < n; i += stride) {
        const float4 a = *(const float4*)&src[i];
        const float4 b = *(const float4*)&src[i + 4];
        f16x8 o;
        o[0] = (_Float16)a.x; o[1] = (_Float16)a.y;
        o[2] = (_Float16)a.z; o[3] = (_Float16)a.w;
        o[4] = (_Float16)b.x; o[5] = (_Float16)b.y;
        o[6] = (_Float16)b.z; o[7] = (_Float16)b.w;
        *(f16x8*)&dst[i] = o;
    }
}

// 64x64-tile transpose to fp16: dst[c][r] = src[r][c]; n=768
__global__ __launch_bounds__(256)
void transpose_f16(const float* __restrict__ src, _Float16* __restrict__ dst, int n)
{
    __shared__ float t[64][65];
    const int tx = threadIdx.x & 63, ty = threadIdx.x >> 6;
    const int r0 = blockIdx.y * 64, c0 = blockIdx.x * 64;
    #pragma unroll
    for (int r = 0; r < 16; ++r) {
        const int row = ty * 16 + r;
        t[row][tx] = src[(size_t)(r0 + row) * n + c0 + tx];
    }
    __syncthreads();
    #pragma unroll
    for (int r = 0; r < 16; ++r) {
        const int orow = ty * 16 + r;
        dst[(size_t)(c0 + orow) * n + r0 + tx] = (_Float16)t[tx][orow];
    }
}

// colvec[d] = sum_e WkT[d][e]*bq[e]
__global__ __launch_bounds__(256)
void colvec_kernel(const _Float16* __restrict__ WkT, const float* __restrict__ bq,
                   float* __restrict__ colvec, int n)
{
    const int wv = threadIdx.x >> 6, lane = threadIdx.x & 63;
    const int d = blockIdx.x * 4 + wv;
    float s = 0.f;
    for (int e = lane; e < n; e += 64)
        s += (float)WkT[(size_t)d * n + e] * bq[e];
    #pragma unroll
    for (int off = 32; off; off >>= 1) s += __shfl_down(s, off, 64);
    if (lane == 0) colvec[d] = s;
}

// cterm[row] = dot(k[row,:], colvec)  (fp32 inputs)
__global__ __launch_bounds__(256)
void cterm_kernel(const float* __restrict__ k, const float* __restrict__ colvec,
                  float* __restrict__ cterm)
{
    const int wv = threadIdx.x >> 6, lane = threadIdx.x & 63;
    const long long row = (long long)blockIdx.x * 4 + wv;
    const float* kp = k + row * 768;
    float s = 0.f;
    #pragma unroll
    for (int i = 0; i < 3; ++i) {
        const float4 a = *(const float4*)&kp[lane * 4 + i * 256];
        const float4 c = *(const float4*)&colvec[lane * 4 + i * 256];
        s += a.x * c.x + a.y * c.y + a.z * c.z + a.w * c.w;
    }
    #pragma unroll
    for (int off = 32; off; off >>= 1) s += __shfl_down(s, off, 64);
    if (lane == 0) cterm[row] = s;
}

// Row softmax with diag mask + per-column bias term; fp16 P written in place.
// Block id XCD-swizzled to match the scores GEMM's chunk map.
__global__ __launch_bounds__(256)
void softmax_diag(float* __restrict__ P, const float* __restrict__ tptr,
                  const float* __restrict__ cterm, int S)
{
    const int p = blockIdx.x;                       // 16384 = 8 * 2048
    const int row = (p & 7) * (16 * 1024 / 8) + (p >> 3);
    const int i   = row % S;
    float* rp = P + (long long)row * S;
    const int tid = threadIdx.x;
    const float invt = 1.0f / tptr[0];

    const float4 v  = *(const float4*)&rp[tid * 4];
    const float4 ct = *(const float4*)&cterm[(long long)(row / S) * S + tid * 4];
    float vals[4] = {v.x + ct.x, v.y + ct.y, v.z + ct.z, v.w + ct.w};
    #pragma unroll
    for (int j = 0; j < 4; ++j) {
        vals[j] *= invt;
        if (tid * 4 + j == i) vals[j] = -INFINITY;
    }

    float mx = fmaxf(fmaxf(vals[0], vals[1]), fmaxf(vals[2], vals[3]));
    #pragma unroll
    for (int off = 32; off > 0; off >>= 1)
        mx = fmaxf(mx, __shfl_down(mx, off, 64));

    __shared__ float smax[4], ssum[4];
    const int wv = tid >> 6, ln = tid & 63;
    if (ln == 0) smax[wv] = mx;
    __syncthreads();
    mx = fmaxf(fmaxf(smax[0], smax[1]), fmaxf(smax[2], smax[3]));

    float e[4];
    float s = 0.f;
    #pragma unroll
    for (int j = 0; j < 4; ++j) { e[j] = expf(vals[j] - mx); s += e[j]; }
    #pragma unroll
    for (int off = 32; off > 0; off >>= 1)
        s += __shfl_down(s, off, 64);
    if (ln == 0) ssum[wv] = s;
    __syncthreads();
    s = ssum[0] + ssum[1] + ssum[2] + ssum[3];

    const float inv = 1.0f / s;
    f16x4 o;
    o[0] = (_Float16)(e[0] * inv);
    o[1] = (_Float16)(e[1] * inv);
    o[2] = (_Float16)(e[2] * inv);
    o[3] = (_Float16)(e[3] * inv);
    *(f16x4*)&((_Float16*)rp)[tid * 4] = o;
}

extern "C" void kernel_launch(void* const* d_in, const int* in_sizes, int n_in,
                              void* d_out, int out_size, void* d_ws, size_t ws_size,
                              hipStream_t stream)
{
    const float* q    = (const float*)d_in[0];
    const float* k    = (const float*)d_in[1];
    const float* v    = (const float*)d_in[2];
    const float* Wq   = (const float*)d_in[3];
    const float* bq   = (const float*)d_in[4];
    const float* Wk   = (const float*)d_in[5];
    const float* bk   = (const float*)d_in[6];   // row-constant -> cancels in softmax
    const float* Wv   = (const float*)d_in[7];
    const float* bv   = (const float*)d_in[8];
    const float* temp = (const float*)d_in[9];
    (void)bk;

    const int S = 1024, D = 768;
    const long long nW = (long long)D * D;       // 589,824

    // ws layout (bytes), end 197,725,184 (< proven 202,574,848). No aliasing.
    char* ws = (char*)d_ws;
    _Float16* qh  = (_Float16*)(ws + 0);          // 24 MB
    _Float16* kh  = (_Float16*)(ws + 25165824);   // 24 MB
    _Float16* vh  = (_Float16*)(ws + 50331648);   // 24 MB
    _Float16* VT  = (_Float16*)(ws + 75497472);   // 24 MB
    _Float16* KG  = (_Float16*)(ws + 100663296);  // 24 MB
    float*  scores = (float*)(ws + 125829120);    // 64 MiB
    _Float16* wvh = (_Float16*)(ws + 192937984);  // 1.125 MB
    _Float16* WqT = (_Float16*)(ws + 194117632);
    _Float16* WkT = (_Float16*)(ws + 195297280);
    _Float16* G   = (_Float16*)(ws + 196476928);
    float* colvec = (float*)(ws + 197656576);
    float* cterm  = (float*)(ws + 197659648);

    dim3 blk(256);
    dim3 blk512(512);

    // input conversions / transposes
    tof16_3<<<dim3(6144, 1, 3), blk, 0, stream>>>(q, k, v, qh, kh, vh);
    tof16_kernel<<<288, blk, 0, stream>>>(Wv, wvh, nW);
    transpose_f16<<<dim3(12, 12), blk, 0, stream>>>(Wq, WqT, D);
    transpose_f16<<<dim3(12, 12), blk, 0, stream>>>(Wk, WkT, D);

    // bias column-term: colvec = WkT*bq ; cterm[b,j] = k[b,j]·colvec
    colvec_kernel<<<192,  blk, 0, stream>>>(WkT, bq, colvec, D);
    cterm_kernel <<<4096, blk, 0, stream>>>(k, colvec, cterm);

    // VT[b][e][s] = sum_d Wv[e,d] v[b,s,d] + bv[e]  (M=768, N=1024, K=768)
    mfma_gemm256<1, 2><<<dim3(4, 3, 16), blk512, 0, stream>>>(
        wvh, vh, bv, VT,
        768, 768, 768, 1024, 0, (long long)S * D, (long long)D * S);

    // G[d,d'] = sum_e Wq[e,d] Wk[e,d']  (tiny, 128^2 path)
    mfma_gemm<1, 0><<<dim3(6, 6, 1), blk, 0, stream>>>(
        WqT, WkT, nullptr, G,
        768, 768, 768, 768, 0, 0, 0);

    // KG[j,d] = sum_d' k[j,d'] G[d,d']  (M=16384 flat, N=768, K=768)
    mfma_gemm256<1, 0><<<dim3(3, 64, 1), blk512, 0, stream>>>(
        kh, G, nullptr, KG,
        768, 768, 768, 768, 0, 0, 0);

    // scores[b] = q[b] (KG[b])^T  (M=N=1024, K=768)
    mfma_gemm256<0, 0><<<dim3(4, 4, 16), blk512, 0, stream>>>(
        qh, KG, nullptr, scores,
        768, 768, 768, 1024,
        (long long)S * D, (long long)S * D, (long long)S * S);

    // masked softmax (+ column bias term), fp16 P written in place
    softmax_diag<<<16 * S, blk, 0, stream>>>(scores, temp, cterm, S);

    // out[b] = P[b] VT[b]^T  (M=1024, N=768, K=1024; P rows stride 2048 fp16)
    mfma_gemm256<0, 0><<<dim3(3, 4, 16), blk512, 0, stream>>>(
        (const _Float16*)scores, VT, nullptr, d_out,
        1024, 2048, 1024, 768,
        2LL * S * S, (long long)D * S, (long long)S * D);
}